// Round 6
// baseline (101.881 us; speedup 1.0000x reference)
//
#include <hip/hip_runtime.h>

// Problem constants
#define BATCH 8
#define HW_N  1024   // 32*32
#define CD    128    // channels
#define W_IMG 32
#define CH_O  30
#define F_N   900    // 30*30

// Workspace layout (bytes)
#define OFF_Q16 0u          // 8192*128*2 = 2 MB
#define OFF_K16 2097152u
#define OFF_V   4194304u    // 32 KB
#define OFF_D   4227072u    // 8192*25*4 = 819200
#define OFF_TP  5046272u    // 8192*8 doubles
#define OFF_TVP 5570560u    // ends 6094848

typedef _Float16 f16x8 __attribute__((ext_vector_type(8)));
typedef _Float16 f16x4 __attribute__((ext_vector_type(4)));
typedef float    f32x4 __attribute__((ext_vector_type(4)));

// MFMA-fragment-order layout for row-major [R][k]:
// off(R,k) = (R>>4)*2048 + [ (k>>5)*4 + ((k>>3)&3) ]*128 + (R&15)*8 + (k&7)
__device__ __forceinline__ size_t frag_off(int R, int k) {
    return (size_t)(R >> 4) * 2048 +
           (size_t)((((k >> 5) * 4 + ((k >> 3) & 3)) * 128) + ((R & 15) * 8) + (k & 7));
}

__device__ __forceinline__ void async16(const void* g, void* l) {
    __builtin_amdgcn_global_load_lds(
        (const __attribute__((address_space(1))) unsigned int*)g,
        (__attribute__((address_space(3))) unsigned int*)l,
        16, 0, 0);
}

// -------------------------------------------------------------------------
// Kernel A: Q/K via single-term fp16 MFMA (storage rounding dominates the
// error budget anyway); V fp32. 512 blocks x 16 rows. Weights read directly
// from fp32 global (L2-hot) and converted inline to B-fragments.
// -------------------------------------------------------------------------
__global__ __launch_bounds__(256) void qkv_kernel(
    const float* __restrict__ xf,
    const float* __restrict__ Wq, const float* __restrict__ bq,
    const float* __restrict__ Wk, const float* __restrict__ bk,
    const float* __restrict__ wv, const float* __restrict__ bv,
    _Float16* __restrict__ Q16, _Float16* __restrict__ K16,
    float* __restrict__ V)
{
    __shared__ float    xs[16][132];
    __shared__ _Float16 xh[2048];

    const int t = threadIdx.x;
    const int rowbase = blockIdx.x * 16;

    // stage 16x128 fp32 rows (for V) + fp16 copy in A-frag order (for MFMA)
#pragma unroll
    for (int m = 0; m < 2; ++m) {
        int id = t + 256 * m;          // 0..511 float4 chunks
        int r  = id >> 5;
        int c4 = id & 31;
        float4 v4 = *(const float4*)&xf[(size_t)(rowbase + r) * CD + c4 * 4];
        *(float4*)&xs[r][c4 * 4] = v4;
        int c = c4 * 4;
        int off = ((c >> 5) * 4 + ((c >> 3) & 3)) * 128 + r * 8 + (c & 7);
        f16x4 hh;
        hh[0] = (_Float16)v4.x; hh[1] = (_Float16)v4.y;
        hh[2] = (_Float16)v4.z; hh[3] = (_Float16)v4.w;
        *(f16x4*)&xh[off] = hh;
    }
    __syncthreads();

    const int w    = t >> 6;
    const int lane = t & 63;
    const int q    = lane >> 4;
    const int i    = lane & 15;

    f32x4 aq[2], ak[2];
#pragma unroll
    for (int ct = 0; ct < 2; ++ct) {
        aq[ct] = (f32x4){0.f, 0.f, 0.f, 0.f};
        ak[ct] = (f32x4){0.f, 0.f, 0.f, 0.f};
    }

#pragma unroll
    for (int ks = 0; ks < 4; ++ks) {
        const int aoff = (ks * 4 + q) * 128 + i * 8;
        f16x8 ah = *(f16x8*)&xh[aoff];
#pragma unroll
        for (int ct = 0; ct < 2; ++ct) {
            const int c = (w * 2 + ct) * 16 + i;       // output col = B-frag row
            const size_t wo = (size_t)c * CD + ks * 32 + q * 8;
            float4 wq0 = *(const float4*)&Wq[wo];
            float4 wq1 = *(const float4*)&Wq[wo + 4];
            float4 wk0 = *(const float4*)&Wk[wo];
            float4 wk1 = *(const float4*)&Wk[wo + 4];
            f16x8 bq8, bk8;
            bq8[0] = (_Float16)wq0.x; bq8[1] = (_Float16)wq0.y;
            bq8[2] = (_Float16)wq0.z; bq8[3] = (_Float16)wq0.w;
            bq8[4] = (_Float16)wq1.x; bq8[5] = (_Float16)wq1.y;
            bq8[6] = (_Float16)wq1.z; bq8[7] = (_Float16)wq1.w;
            bk8[0] = (_Float16)wk0.x; bk8[1] = (_Float16)wk0.y;
            bk8[2] = (_Float16)wk0.z; bk8[3] = (_Float16)wk0.w;
            bk8[4] = (_Float16)wk1.x; bk8[5] = (_Float16)wk1.y;
            bk8[6] = (_Float16)wk1.z; bk8[7] = (_Float16)wk1.w;
            aq[ct] = __builtin_amdgcn_mfma_f32_16x16x32_f16(ah, bq8, aq[ct], 0, 0, 0);
            ak[ct] = __builtin_amdgcn_mfma_f32_16x16x32_f16(ah, bk8, ak[ct], 0, 0, 0);
        }
    }

    // epilogue: bias, single-fp16 store in frag order
#pragma unroll
    for (int ct = 0; ct < 2; ++ct) {
        int c = (w * 2 + ct) * 16 + i;
        float bqv = bq[c], bkv = bk[c];
#pragma unroll
        for (int g = 0; g < 4; ++g) {
            int R = rowbase + q * 4 + g;
            size_t o = frag_off(R, c);
            Q16[o] = (_Float16)(aq[ct][g] + bqv);
            K16[o] = (_Float16)(ak[ct][g] + bkv);
        }
    }

    if (t < 16) {
        float s = 0.f;
#pragma unroll 8
        for (int k = 0; k < CD; ++k) s += xs[t][k] * wv[k];
        V[rowbase + t] = s + bv[0];
    }
}

// -------------------------------------------------------------------------
// Kernel B: S = Q@K^T, single fp16 MFMA term; fused exp/rowsums/band.
// grid (8,8,8); 256 thr = 4 waves 2x2; global_load_lds staging; partials.
// -------------------------------------------------------------------------
#define A_OFF 0
#define B_OFF 16384
#define VS_OFF 32768
#define SCR2 16896
#define ATTN_LDS_TOTAL 33792

__global__ __launch_bounds__(256) void attn_kernel(
    const _Float16* __restrict__ Q16, const _Float16* __restrict__ K16,
    const float* __restrict__ V,
    double* __restrict__ Tp, double* __restrict__ TVp,
    float* __restrict__ D)
{
    extern __shared__ char lds[];
    _Float16* Ah = (_Float16*)(lds + A_OFF);
    _Float16* Bh = (_Float16*)(lds + B_OFF);
    float*    Vs = (float*)(lds + VS_OFF);

    const int b  = blockIdx.x;
    const int rb = blockIdx.y;
    const int cb = blockIdx.z;
    const int t  = threadIdx.x;
    const int w    = t >> 6;
    const int lane = t & 63;
    const int q    = lane >> 4;
    const int i    = lane & 15;
    const int wy = w >> 1, wx = w & 1;

    if (t < 128) Vs[t] = V[b * HW_N + cb * 128 + t];

    f32x4 acc[4][4];
#pragma unroll
    for (int r = 0; r < 4; ++r)
#pragma unroll
        for (int f = 0; f < 4; ++f) acc[r][f] = (f32x4){0.f, 0.f, 0.f, 0.f};

    const size_t abase = (size_t)(b * 8 + rb) * 16384;   // fp16 units
    const size_t bbase = (size_t)(b * 8 + cb) * 16384;

    for (int kh = 0; kh < 2; ++kh) {
        __syncthreads();
#pragma unroll
        for (int m = 0; m < 4; ++m) {
            int id = t + 256 * m;                    // 0..1023, 16B chunks
            size_t goff = (size_t)(id >> 7) * 2048 + kh * 1024 + (id & 127) * 8;
            int loff = id * 8;                       // identity LDS layout
            async16(Q16 + abase + goff, Ah + loff);
            async16(K16 + bbase + goff, Bh + loff);
        }
        asm volatile("s_waitcnt vmcnt(0)" ::: "memory");
        __syncthreads();

#pragma unroll
        for (int kcl = 0; kcl < 2; ++kcl) {
            f16x8 a4[4], b4[4];
#pragma unroll
            for (int r = 0; r < 4; ++r) {
                int ao = (((wy * 4 + r) * 2 + kcl) * 4 + q) * 128 + i * 8;
                a4[r] = *(f16x8*)&Ah[ao];
                int bo = (((wx * 4 + r) * 2 + kcl) * 4 + q) * 128 + i * 8;
                b4[r] = *(f16x8*)&Bh[bo];
            }
#pragma unroll
            for (int r = 0; r < 4; ++r)
#pragma unroll
                for (int f = 0; f < 4; ++f)
                    acc[r][f] = __builtin_amdgcn_mfma_f32_16x16x32_f16(
                        a4[r], b4[f], acc[r][f], 0, 0, 0);
        }
    }

    // ---- epilogue: exp, partial row sums, banded D store ----
    float st[4][4], stv[4][4];
#pragma unroll
    for (int r = 0; r < 4; ++r)
#pragma unroll
        for (int g = 0; g < 4; ++g) { st[r][g] = 0.f; stv[r][g] = 0.f; }

    const bool band = (cb - rb <= 1) && (rb - cb <= 1);

#pragma unroll
    for (int f = 0; f < 4; ++f) {
        int col_local = wx * 64 + f * 16 + i;
        int hw_c = cb * 128 + col_local;
        float v = Vs[col_local];
        int cimg_r = hw_c >> 5, cimg_c = hw_c & 31;
#pragma unroll
        for (int r = 0; r < 4; ++r)
#pragma unroll
            for (int g = 0; g < 4; ++g) {
                float e = __expf(acc[r][f][g]);
                st[r][g]  += e;
                stv[r][g] += e * v;
                if (band) {
                    int row_local = wy * 64 + r * 16 + q * 4 + g;
                    int hw_r = rb * 128 + row_local;
                    int dy = cimg_r - (hw_r >> 5);
                    int dx = cimg_c - (hw_r & 31);
                    if ((unsigned)(dy + 2) <= 4u && (unsigned)(dx + 2) <= 4u)
                        D[(size_t)(b * HW_N + hw_r) * 25 + (dy + 2) * 5 + (dx + 2)] = e;
                }
            }
    }

    // ---- block reduction (scratch aliases staging LDS) -> double partials ----
    __syncthreads();
    float* scrT  = (float*)lds;              // 128 x 33 fp32
    float* scrTV = (float*)(lds + SCR2);
#pragma unroll
    for (int r = 0; r < 4; ++r)
#pragma unroll
        for (int g = 0; g < 4; ++g) {
            int rl = wy * 64 + r * 16 + q * 4 + g;
            scrT [rl * 33 + wx * 16 + i] = st[r][g];
            scrTV[rl * 33 + wx * 16 + i] = stv[r][g];
        }
    __syncthreads();
    if (t < 128) {
        double s = 0.0;
#pragma unroll
        for (int c = 0; c < 32; ++c) s += (double)scrT[t * 33 + c];
        Tp[(size_t)(b * HW_N + rb * 128 + t) * 8 + cb] = s;
    } else {
        int tt = t - 128;
        double s = 0.0;
#pragma unroll
        for (int c = 0; c < 32; ++c) s += (double)scrTV[tt * 33 + c];
        TVp[(size_t)(b * HW_N + rb * 128 + tt) * 8 + cb] = s;
    }
}

// -------------------------------------------------------------------------
// Kernel C: sum partials -> T,TV; gates; out = sum_p gate_p * xf rows.
// grid (30, 8) x 256 threads; vectorized float4 epilogue.
// -------------------------------------------------------------------------
__global__ __launch_bounds__(256) void gate_out_kernel(
    const float* __restrict__ xf, const float* __restrict__ V,
    const double* __restrict__ Tp, const double* __restrict__ TVp,
    const float* __restrict__ D, float* __restrict__ out)
{
    const int fi = blockIdx.x;   // 0..29
    const int b  = blockIdx.y;
    const int t  = threadIdx.x;

    __shared__ float  xs[96 * 128];   // 3 img rows x 32 cols x 128 ch
    __shared__ float  gates[32][9];
    __shared__ double Ts[96], TVs[96];

#pragma unroll
    for (int m = 0; m < 12; ++m) {
        int id   = t + 256 * m;
        int srow = id >> 5;
        int c4   = id & 31;
        int r3   = srow >> 5, colc = srow & 31;
        *(float4*)&xs[srow * 128 + c4 * 4] =
            *(const float4*)&xf[((size_t)(b * 32 + fi + r3) * 32 + colc) * CD + c4 * 4];
    }

    if (t < 96) {
        int R = b * HW_N + (fi + (t >> 5)) * W_IMG + (t & 31);
        double s = 0.0;
#pragma unroll
        for (int c = 0; c < 8; ++c) s += Tp[(size_t)R * 8 + c];
        Ts[t] = s;
    } else if (t >= 128 && t < 224) {
        int tt = t - 128;
        int R = b * HW_N + (fi + (tt >> 5)) * W_IMG + (tt & 31);
        double s = 0.0;
#pragma unroll
        for (int c = 0; c < 8; ++c) s += TVp[(size_t)R * 8 + c];
        TVs[tt] = s;
    }
    __syncthreads();

    for (int g = t; g < 270; g += 256) {
        int fj = g / 9, p = g % 9;
        int pr = p / 3, pc = p % 3;
        int lrow = pr * 32 + fj + pc;
        int ip = (fi + pr) * W_IMG + (fj + pc);
        const float* Drow = &D[(size_t)(b * HW_N + ip) * 25];
        double se = 0.0, sev = 0.0;
#pragma unroll
        for (int qq = 0; qq < 9; ++qq) {
            int qr = qq / 3, qc = qq % 3;
            float e = Drow[(qr - pr + 2) * 5 + (qc - pc + 2)];
            se  += (double)e;
            sev += (double)(e * V[b * HW_N + (fi + qr) * W_IMG + (fj + qc)]);
        }
        double denom = Ts[lrow] - se + 1e-5;
        double numer = TVs[lrow] - sev;
        gates[fj][p] = (float)(numer / denom);
    }
    __syncthreads();

    // vectorized epilogue: thread = (c4 channel-quad, fj lane)
    const int c4  = t & 31;
    const int fjl = t >> 5;      // 0..7
#pragma unroll
    for (int it = 0; it < 4; ++it) {
        int fj = fjl + 8 * it;   // 0..31
        if (fj < CH_O) {
            f32x4 o = (f32x4){0.f, 0.f, 0.f, 0.f};
#pragma unroll
            for (int p = 0; p < 9; ++p) {
                int pr = p / 3, pc = p % 3;
                f32x4 x = *(f32x4*)&xs[(pr * 32 + fj + pc) * 128 + c4 * 4];
                float gv = gates[fj][p];
                o += gv * x;
            }
            *(f32x4*)&out[((size_t)(b * F_N) + fi * CH_O + fj) * CD + c4 * 4] = o;
        }
    }
}

// -------------------------------------------------------------------------
extern "C" void kernel_launch(void* const* d_in, const int* in_sizes, int n_in,
                              void* d_out, int out_size, void* d_ws, size_t ws_size,
                              hipStream_t stream)
{
    (void)in_sizes; (void)n_in; (void)out_size; (void)ws_size;
    const float* batch = (const float*)d_in[0];
    const float* Wq    = (const float*)d_in[1];
    const float* bq    = (const float*)d_in[2];
    const float* Wk    = (const float*)d_in[3];
    const float* bk    = (const float*)d_in[4];
    const float* wv    = (const float*)d_in[5];
    const float* bv    = (const float*)d_in[6];

    char*      ws  = (char*)d_ws;
    _Float16*  Q16 = (_Float16*)(ws + OFF_Q16);
    _Float16*  K16 = (_Float16*)(ws + OFF_K16);
    float*     V   = (float*)(ws + OFF_V);
    float*     D   = (float*)(ws + OFF_D);
    double*    Tp  = (double*)(ws + OFF_TP);
    double*    TVp = (double*)(ws + OFF_TVP);
    float*     out = (float*)d_out;

    qkv_kernel<<<dim3(512), dim3(256), 0, stream>>>(batch, Wq, bq, Wk, bk, wv, bv,
                                                    Q16, K16, V);
    attn_kernel<<<dim3(8, 8, 8), dim3(256), ATTN_LDS_TOTAL, stream>>>(
        Q16, K16, V, Tp, TVp, D);
    gate_out_kernel<<<dim3(CH_O, BATCH), dim3(256), 0, stream>>>(batch, V, Tp, TVp, D, out);
}

// Round 7
// 97.425 us; speedup vs baseline: 1.0457x; 1.0457x over previous
//
#include <hip/hip_runtime.h>

// Problem constants
#define BATCH 8
#define HW_N  1024   // 32*32
#define CD    128    // channels
#define W_IMG 32
#define CH_O  30
#define F_N   900    // 30*30

// Workspace layout (bytes)
#define OFF_Q16 0u          // 8192*128*2 = 2 MB
#define OFF_K16 2097152u
#define OFF_V   4194304u    // 32 KB
#define OFF_D   4227072u    // 8192*25*4 = 819200
#define OFF_TP  5046272u    // 8192*8 doubles
#define OFF_TVP 5570560u    // -> 6094848
#define OFF_WQF 6094848u    // 128*128 fp16 = 32768
#define OFF_WKF 6127616u    // ends 6160384

typedef _Float16 f16x8 __attribute__((ext_vector_type(8)));
typedef _Float16 f16x4 __attribute__((ext_vector_type(4)));
typedef float    f32x4 __attribute__((ext_vector_type(4)));

// MFMA-fragment-order layout for row-major [R][k]:
// off(R,k) = (R>>4)*2048 + [ (k>>5)*4 + ((k>>3)&3) ]*128 + (R&15)*8 + (k&7)
__device__ __forceinline__ size_t frag_off(int R, int k) {
    return (size_t)(R >> 4) * 2048 +
           (size_t)((((k >> 5) * 4 + ((k >> 3) & 3)) * 128) + ((R & 15) * 8) + (k & 7));
}

__device__ __forceinline__ void async16(const void* g, void* l) {
    __builtin_amdgcn_global_load_lds(
        (const __attribute__((address_space(1))) unsigned int*)g,
        (__attribute__((address_space(3))) unsigned int*)l,
        16, 0, 0);
}

// -------------------------------------------------------------------------
// Kernel P: pack Wq, Wk (fp32 row-major) -> single-fp16 frag-order arrays.
// grid 8 x 256; thread -> (channel c, 8-wide k chunk). Coalesced on write
// is irrelevant (one-shot); what matters is qkv's coalesced frag reads.
// -------------------------------------------------------------------------
__global__ __launch_bounds__(256) void prep_kernel(
    const float* __restrict__ Wq, const float* __restrict__ Wk,
    _Float16* __restrict__ WqF, _Float16* __restrict__ WkF)
{
    int id = blockIdx.x * 256 + threadIdx.x;   // 0..2047
    int c  = id >> 4;
    int kc = id & 15;
    size_t src = (size_t)c * CD + kc * 8;
    size_t dst = frag_off(c, kc * 8);

    float vq[8], vk[8];
    *(float4*)&vq[0] = *(const float4*)&Wq[src];
    *(float4*)&vq[4] = *(const float4*)&Wq[src + 4];
    *(float4*)&vk[0] = *(const float4*)&Wk[src];
    *(float4*)&vk[4] = *(const float4*)&Wk[src + 4];

    f16x8 qh, kh;
#pragma unroll
    for (int e = 0; e < 8; ++e) {
        qh[e] = (_Float16)vq[e];
        kh[e] = (_Float16)vk[e];
    }
    *(f16x8*)&WqF[dst] = qh;
    *(f16x8*)&WkF[dst] = kh;
}

// -------------------------------------------------------------------------
// Kernel A: Q/K via single-term fp16 MFMA; V fp32. 512 blocks x 16 rows.
// Weight B-frags read coalesced from packed frag-order fp16 (L2-hot).
// -------------------------------------------------------------------------
__global__ __launch_bounds__(256) void qkv_kernel(
    const float* __restrict__ xf,
    const float* __restrict__ bq, const float* __restrict__ bk,
    const float* __restrict__ wv, const float* __restrict__ bv,
    const _Float16* __restrict__ WqF, const _Float16* __restrict__ WkF,
    _Float16* __restrict__ Q16, _Float16* __restrict__ K16,
    float* __restrict__ V)
{
    __shared__ float    xs[16][132];
    __shared__ _Float16 xh[2048];

    const int t = threadIdx.x;
    const int rowbase = blockIdx.x * 16;

    // stage 16x128 fp32 rows (for V) + fp16 copy in A-frag order (for MFMA)
#pragma unroll
    for (int m = 0; m < 2; ++m) {
        int id = t + 256 * m;          // 0..511 float4 chunks
        int r  = id >> 5;
        int c4 = id & 31;
        float4 v4 = *(const float4*)&xf[(size_t)(rowbase + r) * CD + c4 * 4];
        *(float4*)&xs[r][c4 * 4] = v4;
        int c = c4 * 4;
        int off = ((c >> 5) * 4 + ((c >> 3) & 3)) * 128 + r * 8 + (c & 7);
        f16x4 hh;
        hh[0] = (_Float16)v4.x; hh[1] = (_Float16)v4.y;
        hh[2] = (_Float16)v4.z; hh[3] = (_Float16)v4.w;
        *(f16x4*)&xh[off] = hh;
    }
    __syncthreads();

    const int w    = t >> 6;
    const int lane = t & 63;
    const int q    = lane >> 4;
    const int i    = lane & 15;

    f32x4 aq[2], ak[2];
#pragma unroll
    for (int ct = 0; ct < 2; ++ct) {
        aq[ct] = (f32x4){0.f, 0.f, 0.f, 0.f};
        ak[ct] = (f32x4){0.f, 0.f, 0.f, 0.f};
    }

#pragma unroll
    for (int ks = 0; ks < 4; ++ks) {
        const int aoff = (ks * 4 + q) * 128 + i * 8;
        f16x8 ah = *(f16x8*)&xh[aoff];
#pragma unroll
        for (int ct = 0; ct < 2; ++ct) {
            // B-frag: rows = output cols (w*2+ct)*16.., k-chunk ks. Coalesced:
            // consecutive i -> consecutive 16B within the packed frag block.
            size_t boff = (size_t)(w * 2 + ct) * 2048 + (size_t)(ks * 4 + q) * 128 + i * 8;
            f16x8 bq8 = *(const f16x8*)&WqF[boff];
            f16x8 bk8 = *(const f16x8*)&WkF[boff];
            aq[ct] = __builtin_amdgcn_mfma_f32_16x16x32_f16(ah, bq8, aq[ct], 0, 0, 0);
            ak[ct] = __builtin_amdgcn_mfma_f32_16x16x32_f16(ah, bk8, ak[ct], 0, 0, 0);
        }
    }

    // epilogue: bias, single-fp16 store in frag order
#pragma unroll
    for (int ct = 0; ct < 2; ++ct) {
        int c = (w * 2 + ct) * 16 + i;
        float bqv = bq[c], bkv = bk[c];
#pragma unroll
        for (int g = 0; g < 4; ++g) {
            int R = rowbase + q * 4 + g;
            size_t o = frag_off(R, c);
            Q16[o] = (_Float16)(aq[ct][g] + bqv);
            K16[o] = (_Float16)(ak[ct][g] + bkv);
        }
    }

    if (t < 16) {
        float s = 0.f;
#pragma unroll 8
        for (int k = 0; k < CD; ++k) s += xs[t][k] * wv[k];
        V[rowbase + t] = s + bv[0];
    }
}

// -------------------------------------------------------------------------
// Kernel B: S = Q@K^T, single fp16 MFMA term; fused exp/rowsums/band.
// grid (8,8,8); 256 thr = 4 waves 2x2; global_load_lds staging; partials.
// -------------------------------------------------------------------------
#define A_OFF 0
#define B_OFF 16384
#define VS_OFF 32768
#define SCR2 16896
#define ATTN_LDS_TOTAL 33792

__global__ __launch_bounds__(256) void attn_kernel(
    const _Float16* __restrict__ Q16, const _Float16* __restrict__ K16,
    const float* __restrict__ V,
    double* __restrict__ Tp, double* __restrict__ TVp,
    float* __restrict__ D)
{
    extern __shared__ char lds[];
    _Float16* Ah = (_Float16*)(lds + A_OFF);
    _Float16* Bh = (_Float16*)(lds + B_OFF);
    float*    Vs = (float*)(lds + VS_OFF);

    const int b  = blockIdx.x;
    const int rb = blockIdx.y;
    const int cb = blockIdx.z;
    const int t  = threadIdx.x;
    const int w    = t >> 6;
    const int lane = t & 63;
    const int q    = lane >> 4;
    const int i    = lane & 15;
    const int wy = w >> 1, wx = w & 1;

    if (t < 128) Vs[t] = V[b * HW_N + cb * 128 + t];

    f32x4 acc[4][4];
#pragma unroll
    for (int r = 0; r < 4; ++r)
#pragma unroll
        for (int f = 0; f < 4; ++f) acc[r][f] = (f32x4){0.f, 0.f, 0.f, 0.f};

    const size_t abase = (size_t)(b * 8 + rb) * 16384;   // fp16 units
    const size_t bbase = (size_t)(b * 8 + cb) * 16384;

    for (int kh = 0; kh < 2; ++kh) {
        __syncthreads();
#pragma unroll
        for (int m = 0; m < 4; ++m) {
            int id = t + 256 * m;                    // 0..1023, 16B chunks
            size_t goff = (size_t)(id >> 7) * 2048 + kh * 1024 + (id & 127) * 8;
            int loff = id * 8;                       // identity LDS layout
            async16(Q16 + abase + goff, Ah + loff);
            async16(K16 + bbase + goff, Bh + loff);
        }
        asm volatile("s_waitcnt vmcnt(0)" ::: "memory");
        __syncthreads();

#pragma unroll
        for (int kcl = 0; kcl < 2; ++kcl) {
            f16x8 a4[4], b4[4];
#pragma unroll
            for (int r = 0; r < 4; ++r) {
                int ao = (((wy * 4 + r) * 2 + kcl) * 4 + q) * 128 + i * 8;
                a4[r] = *(f16x8*)&Ah[ao];
                int bo = (((wx * 4 + r) * 2 + kcl) * 4 + q) * 128 + i * 8;
                b4[r] = *(f16x8*)&Bh[bo];
            }
#pragma unroll
            for (int r = 0; r < 4; ++r)
#pragma unroll
                for (int f = 0; f < 4; ++f)
                    acc[r][f] = __builtin_amdgcn_mfma_f32_16x16x32_f16(
                        a4[r], b4[f], acc[r][f], 0, 0, 0);
        }
    }

    // ---- epilogue: exp, partial row sums, banded D store ----
    float st[4][4], stv[4][4];
#pragma unroll
    for (int r = 0; r < 4; ++r)
#pragma unroll
        for (int g = 0; g < 4; ++g) { st[r][g] = 0.f; stv[r][g] = 0.f; }

    const bool band = (cb - rb <= 1) && (rb - cb <= 1);

#pragma unroll
    for (int f = 0; f < 4; ++f) {
        int col_local = wx * 64 + f * 16 + i;
        int hw_c = cb * 128 + col_local;
        float v = Vs[col_local];
        int cimg_r = hw_c >> 5, cimg_c = hw_c & 31;
#pragma unroll
        for (int r = 0; r < 4; ++r)
#pragma unroll
            for (int g = 0; g < 4; ++g) {
                float e = __expf(acc[r][f][g]);
                st[r][g]  += e;
                stv[r][g] += e * v;
                if (band) {
                    int row_local = wy * 64 + r * 16 + q * 4 + g;
                    int hw_r = rb * 128 + row_local;
                    int dy = cimg_r - (hw_r >> 5);
                    int dx = cimg_c - (hw_r & 31);
                    if ((unsigned)(dy + 2) <= 4u && (unsigned)(dx + 2) <= 4u)
                        D[(size_t)(b * HW_N + hw_r) * 25 + (dy + 2) * 5 + (dx + 2)] = e;
                }
            }
    }

    // ---- block reduction (scratch aliases staging LDS) -> double partials ----
    __syncthreads();
    float* scrT  = (float*)lds;              // 128 x 33 fp32
    float* scrTV = (float*)(lds + SCR2);
#pragma unroll
    for (int r = 0; r < 4; ++r)
#pragma unroll
        for (int g = 0; g < 4; ++g) {
            int rl = wy * 64 + r * 16 + q * 4 + g;
            scrT [rl * 33 + wx * 16 + i] = st[r][g];
            scrTV[rl * 33 + wx * 16 + i] = stv[r][g];
        }
    __syncthreads();
    if (t < 128) {
        double s = 0.0;
#pragma unroll
        for (int c = 0; c < 32; ++c) s += (double)scrT[t * 33 + c];
        Tp[(size_t)(b * HW_N + rb * 128 + t) * 8 + cb] = s;
    } else {
        int tt = t - 128;
        double s = 0.0;
#pragma unroll
        for (int c = 0; c < 32; ++c) s += (double)scrTV[tt * 33 + c];
        TVp[(size_t)(b * HW_N + rb * 128 + tt) * 8 + cb] = s;
    }
}

// -------------------------------------------------------------------------
// Kernel C: sum partials -> T,TV; gates; out = sum_p gate_p * xf rows.
// grid (30, 8) x 256 threads; vectorized float4 epilogue.
// -------------------------------------------------------------------------
__global__ __launch_bounds__(256) void gate_out_kernel(
    const float* __restrict__ xf, const float* __restrict__ V,
    const double* __restrict__ Tp, const double* __restrict__ TVp,
    const float* __restrict__ D, float* __restrict__ out)
{
    const int fi = blockIdx.x;   // 0..29
    const int b  = blockIdx.y;
    const int t  = threadIdx.x;

    __shared__ float  xs[96 * 128];   // 3 img rows x 32 cols x 128 ch
    __shared__ float  gates[32][9];
    __shared__ double Ts[96], TVs[96];

#pragma unroll
    for (int m = 0; m < 12; ++m) {
        int id   = t + 256 * m;
        int srow = id >> 5;
        int c4   = id & 31;
        int r3   = srow >> 5, colc = srow & 31;
        *(float4*)&xs[srow * 128 + c4 * 4] =
            *(const float4*)&xf[((size_t)(b * 32 + fi + r3) * 32 + colc) * CD + c4 * 4];
    }

    if (t < 96) {
        int R = b * HW_N + (fi + (t >> 5)) * W_IMG + (t & 31);
        double s = 0.0;
#pragma unroll
        for (int c = 0; c < 8; ++c) s += Tp[(size_t)R * 8 + c];
        Ts[t] = s;
    } else if (t >= 128 && t < 224) {
        int tt = t - 128;
        int R = b * HW_N + (fi + (tt >> 5)) * W_IMG + (tt & 31);
        double s = 0.0;
#pragma unroll
        for (int c = 0; c < 8; ++c) s += TVp[(size_t)R * 8 + c];
        TVs[tt] = s;
    }
    __syncthreads();

    for (int g = t; g < 270; g += 256) {
        int fj = g / 9, p = g % 9;
        int pr = p / 3, pc = p % 3;
        int lrow = pr * 32 + fj + pc;
        int ip = (fi + pr) * W_IMG + (fj + pc);
        const float* Drow = &D[(size_t)(b * HW_N + ip) * 25];
        double se = 0.0, sev = 0.0;
#pragma unroll
        for (int qq = 0; qq < 9; ++qq) {
            int qr = qq / 3, qc = qq % 3;
            float e = Drow[(qr - pr + 2) * 5 + (qc - pc + 2)];
            se  += (double)e;
            sev += (double)(e * V[b * HW_N + (fi + qr) * W_IMG + (fj + qc)]);
        }
        double denom = Ts[lrow] - se + 1e-5;
        double numer = TVs[lrow] - sev;
        gates[fj][p] = (float)(numer / denom);
    }
    __syncthreads();

    // vectorized epilogue: thread = (c4 channel-quad, fj lane)
    const int c4  = t & 31;
    const int fjl = t >> 5;      // 0..7
#pragma unroll
    for (int it = 0; it < 4; ++it) {
        int fj = fjl + 8 * it;   // 0..31
        if (fj < CH_O) {
            f32x4 o = (f32x4){0.f, 0.f, 0.f, 0.f};
#pragma unroll
            for (int p = 0; p < 9; ++p) {
                int pr = p / 3, pc = p % 3;
                f32x4 x = *(f32x4*)&xs[(pr * 32 + fj + pc) * 128 + c4 * 4];
                float gv = gates[fj][p];
                o += gv * x;
            }
            *(f32x4*)&out[((size_t)(b * F_N) + fi * CH_O + fj) * CD + c4 * 4] = o;
        }
    }
}

// -------------------------------------------------------------------------
extern "C" void kernel_launch(void* const* d_in, const int* in_sizes, int n_in,
                              void* d_out, int out_size, void* d_ws, size_t ws_size,
                              hipStream_t stream)
{
    (void)in_sizes; (void)n_in; (void)out_size; (void)ws_size;
    const float* batch = (const float*)d_in[0];
    const float* Wq    = (const float*)d_in[1];
    const float* bq    = (const float*)d_in[2];
    const float* Wk    = (const float*)d_in[3];
    const float* bk    = (const float*)d_in[4];
    const float* wv    = (const float*)d_in[5];
    const float* bv    = (const float*)d_in[6];

    char*      ws  = (char*)d_ws;
    _Float16*  Q16 = (_Float16*)(ws + OFF_Q16);
    _Float16*  K16 = (_Float16*)(ws + OFF_K16);
    float*     V   = (float*)(ws + OFF_V);
    float*     D   = (float*)(ws + OFF_D);
    double*    Tp  = (double*)(ws + OFF_TP);
    double*    TVp = (double*)(ws + OFF_TVP);
    _Float16*  WqF = (_Float16*)(ws + OFF_WQF);
    _Float16*  WkF = (_Float16*)(ws + OFF_WKF);
    float*     out = (float*)d_out;

    prep_kernel<<<dim3(8), dim3(256), 0, stream>>>(Wq, Wk, WqF, WkF);
    qkv_kernel<<<dim3(512), dim3(256), 0, stream>>>(batch, bq, bk, wv, bv,
                                                    WqF, WkF, Q16, K16, V);
    attn_kernel<<<dim3(8, 8, 8), dim3(256), ATTN_LDS_TOTAL, stream>>>(
        Q16, K16, V, Tp, TVp, D);
    gate_out_kernel<<<dim3(CH_O, BATCH), dim3(256), 0, stream>>>(batch, V, Tp, TVp, D, out);
}